// Round 1
// baseline (107.211 us; speedup 1.0000x reference)
//
#include <hip/hip_runtime.h>

// coef[b] = tanh(dot(Ws[b,:], A_w[0,:]) + A_b[0]); d == 1 in this problem.
__global__ void coef_kernel(const float* __restrict__ Ws,
                            const float* __restrict__ A_w,
                            const float* __restrict__ A_b,
                            float* __restrict__ coef,
                            int b, int input_dim) {
    int bi = blockIdx.x * blockDim.x + threadIdx.x;
    if (bi < b) {
        float acc = A_b[0];
        const float* w = Ws + (size_t)bi * input_dim;
        for (int k = 0; k < input_dim; ++k) acc += w[k] * A_w[k];
        coef[bi] = tanhf(acc);
    }
}

// out[b,i,j] = exp(-((Xs[b,i]*coef[b] - Ys[b,j])^2))
// One block per (b,i) row; threads stride float4 across j.
__global__ void __launch_bounds__(256)
me_kernel(const float* __restrict__ Xs,
          const float* __restrict__ Ys,
          const float* __restrict__ coef,
          float* __restrict__ out,
          int N) {
    const int row  = blockIdx.x;       // row in [0, b*N)
    const int bIdx = row / N;
    const float xi = Xs[row] * coef[bIdx];

    const float4* __restrict__ Y4 = reinterpret_cast<const float4*>(Ys + (size_t)bIdx * N);
    float4* __restrict__ O4 = reinterpret_cast<float4*>(out + (size_t)row * N);
    const int nvec = N >> 2;           // N = 8192, divisible by 4

    for (int v = threadIdx.x; v < nvec; v += blockDim.x) {
        float4 y = Y4[v];
        float dx = xi - y.x;
        float dy = xi - y.y;
        float dz = xi - y.z;
        float dw = xi - y.w;
        float4 o;
        o.x = __expf(-(dx * dx));
        o.y = __expf(-(dy * dy));
        o.z = __expf(-(dz * dz));
        o.w = __expf(-(dw * dw));
        O4[v] = o;
    }
}

extern "C" void kernel_launch(void* const* d_in, const int* in_sizes, int n_in,
                              void* d_out, int out_size, void* d_ws, size_t ws_size,
                              hipStream_t stream) {
    const float* Xs  = (const float*)d_in[0];
    const float* Ys  = (const float*)d_in[1];
    const float* Ws  = (const float*)d_in[2];
    const float* A_w = (const float*)d_in[3];
    const float* A_b = (const float*)d_in[4];
    float* out = (float*)d_out;

    const int d         = in_sizes[4];              // 1
    const int input_dim = in_sizes[3] / d;          // 64
    const int b         = in_sizes[2] / input_dim;  // 2
    const int N         = in_sizes[0] / (b * d);    // 8192

    float* coef = (float*)d_ws;                     // b floats of scratch

    coef_kernel<<<1, 64, 0, stream>>>(Ws, A_w, A_b, coef, b, input_dim);
    me_kernel<<<b * N, 256, 0, stream>>>(Xs, Ys, coef, out, N);
}

// Round 3
// 88.901 us; speedup vs baseline: 1.2060x; 1.2060x over previous
//
#include <hip/hip_runtime.h>

typedef float f32x4 __attribute__((ext_vector_type(4)));

// out[b,i,j] = exp(-((Xs[b,i]*coef[b] - Ys[b,j])^2)),  coef[b] = tanh(Ws[b,:]·A_w[0,:] + A_b[0])
// One block per 4 consecutive rows (same batch); threads stride float4 across j.
// coef is recomputed per block (uniform 64-FMA dot product — scalarized, ~free).
__global__ void __launch_bounds__(256)
me_kernel(const float* __restrict__ Xs,
          const float* __restrict__ Ys,
          const float* __restrict__ Ws,
          const float* __restrict__ A_w,
          const float* __restrict__ A_b,
          float* __restrict__ out,
          int N, int input_dim) {
    const int ROWS = 4;
    const int blocksPerBatch = N / ROWS;          // 2048
    const int bIdx = blockIdx.x / blocksPerBatch;
    const int r0   = blockIdx.x * ROWS;           // global row (batch-contiguous)

    // coef[bIdx]: uniform across the block -> scalar ALU
    float acc = A_b[0];
    const float* __restrict__ w = Ws + (size_t)bIdx * input_dim;
    #pragma unroll 16
    for (int k = 0; k < input_dim; ++k) acc += w[k] * A_w[k];
    const float coef = tanhf(acc);

    const float x0 = Xs[r0 + 0] * coef;
    const float x1 = Xs[r0 + 1] * coef;
    const float x2 = Xs[r0 + 2] * coef;
    const float x3 = Xs[r0 + 3] * coef;

    const f32x4* __restrict__ Y4 = reinterpret_cast<const f32x4*>(Ys + (size_t)bIdx * N);
    f32x4* __restrict__ O0 = reinterpret_cast<f32x4*>(out + (size_t)(r0 + 0) * N);
    f32x4* __restrict__ O1 = reinterpret_cast<f32x4*>(out + (size_t)(r0 + 1) * N);
    f32x4* __restrict__ O2 = reinterpret_cast<f32x4*>(out + (size_t)(r0 + 2) * N);
    f32x4* __restrict__ O3 = reinterpret_cast<f32x4*>(out + (size_t)(r0 + 3) * N);

    const int nvec = N >> 2;                      // 2048

    for (int v = threadIdx.x; v < nvec; v += 256) {
        const f32x4 y = Y4[v];
        f32x4 o0, o1, o2, o3;
        {
            float a = x0 - y.x, b2 = x0 - y.y, c = x0 - y.z, e = x0 - y.w;
            o0.x = __expf(-(a * a)); o0.y = __expf(-(b2 * b2));
            o0.z = __expf(-(c * c)); o0.w = __expf(-(e * e));
        }
        {
            float a = x1 - y.x, b2 = x1 - y.y, c = x1 - y.z, e = x1 - y.w;
            o1.x = __expf(-(a * a)); o1.y = __expf(-(b2 * b2));
            o1.z = __expf(-(c * c)); o1.w = __expf(-(e * e));
        }
        {
            float a = x2 - y.x, b2 = x2 - y.y, c = x2 - y.z, e = x2 - y.w;
            o2.x = __expf(-(a * a)); o2.y = __expf(-(b2 * b2));
            o2.z = __expf(-(c * c)); o2.w = __expf(-(e * e));
        }
        {
            float a = x3 - y.x, b2 = x3 - y.y, c = x3 - y.z, e = x3 - y.w;
            o3.x = __expf(-(a * a)); o3.y = __expf(-(b2 * b2));
            o3.z = __expf(-(c * c)); o3.w = __expf(-(e * e));
        }
        __builtin_nontemporal_store(o0, &O0[v]);
        __builtin_nontemporal_store(o1, &O1[v]);
        __builtin_nontemporal_store(o2, &O2[v]);
        __builtin_nontemporal_store(o3, &O3[v]);
    }
}

extern "C" void kernel_launch(void* const* d_in, const int* in_sizes, int n_in,
                              void* d_out, int out_size, void* d_ws, size_t ws_size,
                              hipStream_t stream) {
    const float* Xs  = (const float*)d_in[0];
    const float* Ys  = (const float*)d_in[1];
    const float* Ws  = (const float*)d_in[2];
    const float* A_w = (const float*)d_in[3];
    const float* A_b = (const float*)d_in[4];
    float* out = (float*)d_out;

    const int d         = in_sizes[4];              // 1
    const int input_dim = in_sizes[3] / d;          // 64
    const int b         = in_sizes[2] / input_dim;  // 2
    const int N         = in_sizes[0] / (b * d);    // 8192

    const int ROWS = 4;
    me_kernel<<<(b * N) / ROWS, 256, 0, stream>>>(Xs, Ys, Ws, A_w, A_b, out, N, input_dim);
}